// Round 1
// baseline (725.224 us; speedup 1.0000x reference)
//
#include <hip/hip_runtime.h>
#include <hip/hip_bf16.h>

#define NN 32768
#define EE 524288
#define GG 512
#define HH 128

// ---------------- CSR build ----------------
__global__ void count_kernel(const int* __restrict__ src, int* __restrict__ cnt) {
    int e = blockIdx.x * 256 + threadIdx.x;
    if (e < EE) atomicAdd(&cnt[src[e]], 1);
}

// single block, 1024 threads, each owns 32 consecutive counts
__global__ void scan_kernel(const int* __restrict__ cnt, int* __restrict__ row_start) {
    int tid = threadIdx.x;
    int base = tid * 32;
    int vals[32];
    int s = 0;
    #pragma unroll
    for (int i = 0; i < 32; ++i) { vals[i] = cnt[base + i]; s += vals[i]; }
    int lane = tid & 63, wave = tid >> 6;
    int incl = s;
    #pragma unroll
    for (int off = 1; off < 64; off <<= 1) {
        int t = __shfl_up(incl, off);
        if (lane >= off) incl += t;
    }
    __shared__ int wave_tot[16];
    if (lane == 63) wave_tot[wave] = incl;
    __syncthreads();
    int wave_base = 0;
    for (int w = 0; w < wave; ++w) wave_base += wave_tot[w];
    int run = wave_base + incl - s;   // exclusive prefix for this thread's segment
    #pragma unroll
    for (int i = 0; i < 32; ++i) { row_start[base + i] = run; run += vals[i]; }
    if (tid == 1023) row_start[NN] = run;
}

__global__ void fill_kernel(const int* __restrict__ src, const int* __restrict__ dst,
                            const float* __restrict__ w, const int* __restrict__ row_start,
                            int* __restrict__ cursor, int* __restrict__ csr_dst,
                            float* __restrict__ csr_w) {
    int e = blockIdx.x * 256 + threadIdx.x;
    if (e < EE) {
        int s = src[e];
        int p = row_start[s] + atomicAdd(&cursor[s], 1);
        csr_dst[p] = dst[e];
        csr_w[p] = w[e];
    }
}

// ---------------- aggregation: h2 = h + sum_{e: src=i} w_e * h[dst_e] ----------------
template<int D>
__global__ __launch_bounds__(256) void aggregate(const float* __restrict__ h,
                                                 const int* __restrict__ row_start,
                                                 const int* __restrict__ csr_dst,
                                                 const float* __restrict__ csr_w,
                                                 float* __restrict__ h2) {
    int node = blockIdx.x * 4 + (threadIdx.x >> 6);
    int lane = threadIdx.x & 63;
    int s = row_start[node], e = row_start[node + 1];
    float acc0 = h[(size_t)node * D + lane];
    float acc1 = 0.f;
    if (D == 128) acc1 = h[(size_t)node * D + 64 + lane];
    for (int base = s; base < e; base += 64) {
        int n = e - base; if (n > 64) n = 64;
        int d = 0; float w = 0.f;
        if (lane < n) { d = csr_dst[base + lane]; w = csr_w[base + lane]; }
        #pragma unroll 4
        for (int j = 0; j < n; ++j) {
            int dj = __shfl(d, j);
            float wj = __shfl(w, j);
            acc0 += wj * h[(size_t)dj * D + lane];
            if (D == 128) acc1 += wj * h[(size_t)dj * D + 64 + lane];
        }
    }
    h2[(size_t)node * D + lane] = acc0;
    if (D == 128) h2[(size_t)node * D + 64 + lane] = acc1;
}

// ---------------- GEMM: out[N,128] = act(A[N,K] @ W[K,128] + bias) ----------------
// BM=64 rows/block, full 128 cols, BK=16. 256 threads, thread tile 8x4.
template<int K, bool RELU, bool DUAL>
__global__ __launch_bounds__(256) void gemm128(const float* __restrict__ A,
                                               const float* __restrict__ W,
                                               const float* __restrict__ bias,
                                               float* __restrict__ out,
                                               const float* __restrict__ g,
                                               const float* __restrict__ be,
                                               const float* __restrict__ m,
                                               const float* __restrict__ v,
                                               float* __restrict__ out_bn) {
    __shared__ float lds_a[16][64];   // [kk][row]
    __shared__ float lds_w[16][128];  // [kk][col]
    int tid = threadIdx.x;
    int block_row = blockIdx.x * 64;
    int tx = tid & 31;        // col group: cols 4*tx .. 4*tx+3
    int ty = tid >> 5;        // row group: rows 8*ty .. 8*ty+7
    float acc[8][4];
    #pragma unroll
    for (int i = 0; i < 8; ++i)
        #pragma unroll
        for (int j = 0; j < 4; ++j) acc[i][j] = 0.f;

    for (int k0 = 0; k0 < K; k0 += 16) {
        // stage A^T tile: 64 rows x 16 k
        {
            int r = tid >> 2;
            int kq = (tid & 3) * 4;
            const float4 av = *(const float4*)(A + (size_t)(block_row + r) * K + k0 + kq);
            lds_a[kq + 0][r] = av.x;
            lds_a[kq + 1][r] = av.y;
            lds_a[kq + 2][r] = av.z;
            lds_a[kq + 3][r] = av.w;
        }
        // stage W tile: 16 x 128
        {
            int kk = tid >> 5;
            int c4 = (tid & 31) * 4;
            *(float4*)&lds_w[kk][c4]     = *(const float4*)(W + (size_t)(k0 + kk) * 128 + c4);
            *(float4*)&lds_w[kk + 8][c4] = *(const float4*)(W + (size_t)(k0 + kk + 8) * 128 + c4);
        }
        __syncthreads();
        #pragma unroll
        for (int kk = 0; kk < 16; ++kk) {
            float4 wv = *(const float4*)&lds_w[kk][tx * 4];
            float4 alo = *(const float4*)&lds_a[kk][ty * 8];
            float4 ahi = *(const float4*)&lds_a[kk][ty * 8 + 4];
            float a[8] = {alo.x, alo.y, alo.z, alo.w, ahi.x, ahi.y, ahi.z, ahi.w};
            float wj[4] = {wv.x, wv.y, wv.z, wv.w};
            #pragma unroll
            for (int i = 0; i < 8; ++i)
                #pragma unroll
                for (int j = 0; j < 4; ++j) acc[i][j] += a[i] * wj[j];
        }
        __syncthreads();
    }

    int col = tx * 4;
    float4 bv = *(const float4*)&bias[col];
    float b[4] = {bv.x, bv.y, bv.z, bv.w};
    float scl[4], sft[4];
    if (DUAL) {
        #pragma unroll
        for (int j = 0; j < 4; ++j) {
            int c = col + j;
            float s = g[c] * rsqrtf(v[c] + 1e-3f);
            scl[j] = s;
            sft[j] = be[c] - m[c] * s;
        }
    }
    #pragma unroll
    for (int i = 0; i < 8; ++i) {
        int row = block_row + ty * 8 + i;
        float o[4];
        #pragma unroll
        for (int j = 0; j < 4; ++j) {
            o[j] = acc[i][j] + b[j];
            if (RELU) o[j] = fmaxf(o[j], 0.f);
        }
        *(float4*)&out[(size_t)row * 128 + col] = make_float4(o[0], o[1], o[2], o[3]);
        if (DUAL) {
            float ob[4];
            #pragma unroll
            for (int j = 0; j < 4; ++j) ob[j] = o[j] * scl[j] + sft[j];
            *(float4*)&out_bn[(size_t)row * 128 + col] = make_float4(ob[0], ob[1], ob[2], ob[3]);
        }
    }
}

// ---------------- pooling: pools[g, col_off + c] += h[i, c] over nodes in graph g ----------------
__global__ __launch_bounds__(128) void pool_kernel(const float* __restrict__ h,
                                                   const int* __restrict__ gidx,
                                                   float* __restrict__ pools, int col_off) {
    const int CHUNK = 64;
    int c = threadIdx.x;
    int i0 = blockIdx.x * CHUNK;
    float acc = 0.f;
    int cur_g = gidx[i0];
    for (int i = i0; i < i0 + CHUNK; ++i) {
        int gi = gidx[i];
        if (gi != cur_g) {
            atomicAdd(&pools[(size_t)cur_g * 640 + col_off + c], acc);
            acc = 0.f;
            cur_g = gi;
        }
        acc += h[(size_t)i * 128 + c];
    }
    atomicAdd(&pools[(size_t)cur_g * 640 + col_off + c], acc);
}

// ---------------- readout ----------------
__global__ __launch_bounds__(128) void readout1(const float* __restrict__ pools,
                                                const float* __restrict__ Wm1,
                                                const float* __restrict__ bm1,
                                                float* __restrict__ t2) {
    __shared__ float row[640];
    int gb = blockIdx.x;
    for (int k = threadIdx.x; k < 640; k += 128) row[k] = pools[(size_t)gb * 640 + k];
    __syncthreads();
    int j = threadIdx.x;
    float acc = bm1[j];
    for (int k = 0; k < 640; ++k) acc += row[k] * Wm1[(size_t)k * 128 + j];
    t2[(size_t)gb * 128 + j] = fmaxf(acc, 0.f);
}

__global__ __launch_bounds__(256) void readout2(const float* __restrict__ t2,
                                                const float* __restrict__ Wm2,
                                                const float* __restrict__ bm2,
                                                float* __restrict__ out) {
    int idx = blockIdx.x * 256 + threadIdx.x;
    if (idx < GG * 2) {
        int gb = idx >> 1, c = idx & 1;
        float acc = bm2[c];
        for (int k = 0; k < 128; ++k) acc += t2[(size_t)gb * 128 + k] * Wm2[k * 2 + c];
        out[idx] = acc;
    }
}

extern "C" void kernel_launch(void* const* d_in, const int* in_sizes, int n_in,
                              void* d_out, int out_size, void* d_ws, size_t ws_size,
                              hipStream_t stream) {
    const float* x  = (const float*)d_in[0];
    const float* ew = (const float*)d_in[1];
    const float *W1[5], *b1[5], *W2[5], *b2[5];
    for (int l = 0; l < 5; ++l) {
        W1[l] = (const float*)d_in[2 + 4 * l];
        b1[l] = (const float*)d_in[3 + 4 * l];
        W2[l] = (const float*)d_in[4 + 4 * l];
        b2[l] = (const float*)d_in[5 + 4 * l];
    }
    const float *bg[3], *bb[3], *bm[3], *bv[3];
    for (int j = 0; j < 3; ++j) {
        bg[j] = (const float*)d_in[22 + 4 * j];
        bb[j] = (const float*)d_in[23 + 4 * j];
        bm[j] = (const float*)d_in[24 + 4 * j];
        bv[j] = (const float*)d_in[25 + 4 * j];
    }
    const float* Wm1 = (const float*)d_in[34];
    const float* bm1 = (const float*)d_in[35];
    const float* Wm2 = (const float*)d_in[36];
    const float* bm2 = (const float*)d_in[37];
    const int* edge_index = (const int*)d_in[38];
    const int* src = edge_index;
    const int* dst = edge_index + EE;
    const int* gidx = (const int*)d_in[39];

    char* p = (char*)d_ws;
    auto alloc = [&](size_t bytes) -> void* {
        void* r = (void*)p;
        p += (bytes + 255) & ~(size_t)255;
        return r;
    };
    int*   csr_dst   = (int*)alloc(EE * 4);
    float* csr_w     = (float*)alloc(EE * 4);
    int*   row_start = (int*)alloc((NN + 1) * 4);
    int*   cnt       = (int*)alloc(NN * 4);
    int*   cursor    = (int*)alloc(NN * 4);
    float* h2        = (float*)alloc((size_t)NN * 128 * 4);
    float* t         = (float*)alloc((size_t)NN * 128 * 4);
    float* h_raw     = (float*)alloc((size_t)NN * 128 * 4);
    float* h_bn      = (float*)alloc((size_t)NN * 128 * 4);
    float* pools     = (float*)alloc((size_t)GG * 640 * 4);
    float* t2        = (float*)alloc((size_t)GG * 128 * 4);

    hipMemsetAsync(cnt, 0, NN * 4, stream);
    hipMemsetAsync(cursor, 0, NN * 4, stream);
    hipMemsetAsync(pools, 0, (size_t)GG * 640 * 4, stream);

    count_kernel<<<EE / 256, 256, 0, stream>>>(src, cnt);
    scan_kernel<<<1, 1024, 0, stream>>>(cnt, row_start);
    fill_kernel<<<EE / 256, 256, 0, stream>>>(src, dst, ew, row_start, cursor, csr_dst, csr_w);

    // bn params used AFTER layer l to produce next input / pooled h5:
    // l=0 -> bn1, l=1 -> bn1, l=2 -> bn2, l=3 -> bn3, l=4 -> bn3
    const int bnsel[5] = {0, 0, 1, 2, 2};

    const float* h_in = x;
    for (int l = 0; l < 5; ++l) {
        if (l == 0) {
            aggregate<64><<<NN / 4, 256, 0, stream>>>(h_in, row_start, csr_dst, csr_w, h2);
            gemm128<64, true, false><<<NN / 64, 256, 0, stream>>>(
                h2, W1[0], b1[0], t, nullptr, nullptr, nullptr, nullptr, nullptr);
        } else {
            aggregate<128><<<NN / 4, 256, 0, stream>>>(h_in, row_start, csr_dst, csr_w, h2);
            gemm128<128, true, false><<<NN / 64, 256, 0, stream>>>(
                h2, W1[l], b1[l], t, nullptr, nullptr, nullptr, nullptr, nullptr);
        }
        int s = bnsel[l];
        gemm128<128, false, true><<<NN / 64, 256, 0, stream>>>(
            t, W2[l], b2[l], h_raw, bg[s], bb[s], bm[s], bv[s], h_bn);
        pool_kernel<<<NN / 64, 128, 0, stream>>>((l < 4) ? h_raw : h_bn, gidx, pools, l * 128);
        h_in = h_bn;
    }

    readout1<<<GG, 128, 0, stream>>>(pools, Wm1, bm1, t2);
    readout2<<<(GG * 2 + 255) / 256, 256, 0, stream>>>(t2, Wm2, bm2, (float*)d_out);
}

// Round 2
// 662.538 us; speedup vs baseline: 1.0946x; 1.0946x over previous
//
#include <hip/hip_runtime.h>
#include <hip/hip_bf16.h>

#define NN 32768
#define EE 524288
#define GG 512
#define HH 128

typedef __bf16 bf16x8 __attribute__((ext_vector_type(8)));
typedef float  f32x4  __attribute__((ext_vector_type(4)));

static __device__ __forceinline__ float bf2f(unsigned short u) {
    union { unsigned int i; float f; } v; v.i = ((unsigned int)u) << 16; return v.f;
}
static __device__ __forceinline__ unsigned short f2bf(float f) {
    __bf16 b = (__bf16)f;
    return __builtin_bit_cast(unsigned short, b);
}

// ---------------- CSR build ----------------
__global__ void count_kernel(const int* __restrict__ src, int* __restrict__ cnt) {
    int e = blockIdx.x * 256 + threadIdx.x;
    if (e < EE) atomicAdd(&cnt[src[e]], 1);
}

// single block, 1024 threads, each owns 32 consecutive counts
__global__ void scan_kernel(const int* __restrict__ cnt, int* __restrict__ row_start) {
    int tid = threadIdx.x;
    int base = tid * 32;
    int vals[32];
    int s = 0;
    #pragma unroll
    for (int i = 0; i < 32; ++i) { vals[i] = cnt[base + i]; s += vals[i]; }
    int lane = tid & 63, wave = tid >> 6;
    int incl = s;
    #pragma unroll
    for (int off = 1; off < 64; off <<= 1) {
        int t = __shfl_up(incl, off);
        if (lane >= off) incl += t;
    }
    __shared__ int wave_tot[16];
    if (lane == 63) wave_tot[wave] = incl;
    __syncthreads();
    int wave_base = 0;
    for (int w = 0; w < wave; ++w) wave_base += wave_tot[w];
    int run = wave_base + incl - s;
    #pragma unroll
    for (int i = 0; i < 32; ++i) { row_start[base + i] = run; run += vals[i]; }
    if (tid == 1023) row_start[NN] = run;
}

// cursor pre-initialized to row_start copy; single 8B interleaved store per edge
__global__ void fill_kernel(const int* __restrict__ src, const int* __restrict__ dst,
                            const float* __restrict__ w,
                            int* __restrict__ cursor, int2* __restrict__ csr) {
    int e = blockIdx.x * 256 + threadIdx.x;
    if (e < EE) {
        int s = src[e];
        int p = atomicAdd(&cursor[s], 1);
        csr[p] = make_int2(dst[e], __float_as_int(w[e]));
    }
}

// ---------------- weight / input conversion to bf16 ----------------
struct WJob { const float* in; unsigned short* out; int K; };
struct WJobs { WJob j[10]; };

// one block per matrix: out[c*K+k] = bf16(in[k*128+c])  (transpose)
__global__ __launch_bounds__(256) void convert_w(WJobs jobs) {
    WJob jb = jobs.j[blockIdx.x];
    int tot = jb.K * 128;
    for (int idx = threadIdx.x; idx < tot; idx += 256) {
        int k = idx >> 7, c = idx & 127;
        jb.out[c * jb.K + k] = f2bf(jb.in[idx]);
    }
}

__global__ __launch_bounds__(256) void convert_x(const float* __restrict__ x,
                                                 unsigned short* __restrict__ xb) {
    int idx = blockIdx.x * 256 + threadIdx.x;
    if (idx < NN * 64) xb[idx] = f2bf(x[idx]);
}

// ---------------- aggregation (bf16 in/out, fp32 accum) ----------------
// h2[i] = h[i] + sum_{e: src=i} w_e * h[dst_e]
template<int D>
__global__ __launch_bounds__(256) void aggregate_bf(const unsigned short* __restrict__ h,
                                                    const int* __restrict__ row_start,
                                                    const int2* __restrict__ csr,
                                                    unsigned short* __restrict__ h2) {
    int node = blockIdx.x * 4 + (threadIdx.x >> 6);
    int lane = threadIdx.x & 63;
    int s = row_start[node], e = row_start[node + 1];
    float acc0, acc1;
    if (D == 128) {
        const unsigned int* hp = (const unsigned int*)h;
        unsigned int self = hp[(size_t)node * 64 + lane];
        acc0 = bf2f((unsigned short)(self & 0xffff));
        acc1 = bf2f((unsigned short)(self >> 16));
        for (int base = s; base < e; base += 64) {
            int n = e - base; if (n > 64) n = 64;
            int dj = 0, wb = 0;
            if (lane < n) { int2 ev = csr[base + lane]; dj = ev.x; wb = ev.y; }
            #pragma unroll 4
            for (int j = 0; j < n; ++j) {
                int d = __shfl(dj, j);
                float w = __int_as_float(__shfl(wb, j));
                unsigned int hv = hp[(size_t)d * 64 + lane];
                acc0 += w * bf2f((unsigned short)(hv & 0xffff));
                acc1 += w * bf2f((unsigned short)(hv >> 16));
            }
        }
        unsigned int* op = (unsigned int*)h2;
        op[(size_t)node * 64 + lane] = (unsigned int)f2bf(acc0) | ((unsigned int)f2bf(acc1) << 16);
    } else {  // D == 64
        unsigned short self = h[(size_t)node * 64 + lane];
        acc0 = bf2f(self);
        for (int base = s; base < e; base += 64) {
            int n = e - base; if (n > 64) n = 64;
            int dj = 0, wb = 0;
            if (lane < n) { int2 ev = csr[base + lane]; dj = ev.x; wb = ev.y; }
            #pragma unroll 4
            for (int j = 0; j < n; ++j) {
                int d = __shfl(dj, j);
                float w = __int_as_float(__shfl(wb, j));
                acc0 += w * bf2f(h[(size_t)d * 64 + lane]);
            }
        }
        h2[(size_t)node * 64 + lane] = f2bf(acc0);
    }
}

// ---------------- MFMA GEMM: A[N,K]bf16 @ Wt[128,K]bf16 ----------------
// block = 256 thr = 4 waves; wave handles 16 rows x 128 cols (8 col-tiles of 16x16x32)
// C/D layout: col = lane&15, row = (lane>>4)*4 + reg   [m89-verified]
template<int K, bool RELU, bool DUAL, bool POOLBN>
__global__ __launch_bounds__(256) void gemm_mfma(const unsigned short* __restrict__ A,
                                                 const unsigned short* __restrict__ Wt,
                                                 const float* __restrict__ bias,
                                                 unsigned short* __restrict__ out_bf,
                                                 float* __restrict__ out_f32,
                                                 const float* __restrict__ g,
                                                 const float* __restrict__ be,
                                                 const float* __restrict__ m,
                                                 const float* __restrict__ v) {
    constexpr int KS = K / 32;
    int tid = threadIdx.x;
    int wave = tid >> 6, lane = tid & 63;
    int mrow = lane & 15, quad = lane >> 4;
    int row = blockIdx.x * 64 + wave * 16 + mrow;

    const bf16x8* Arow = (const bf16x8*)(A + (size_t)row * K);
    bf16x8 a[KS];
    #pragma unroll
    for (int kk = 0; kk < KS; ++kk) a[kk] = Arow[kk * 4 + quad];

    f32x4 acc[8];
    #pragma unroll
    for (int c = 0; c < 8; ++c) acc[c] = (f32x4){0.f, 0.f, 0.f, 0.f};

    #pragma unroll
    for (int c = 0; c < 8; ++c) {
        const bf16x8* Brow = (const bf16x8*)(Wt + (size_t)(c * 16 + mrow) * K);
        #pragma unroll
        for (int kk = 0; kk < KS; ++kk) {
            acc[c] = __builtin_amdgcn_mfma_f32_16x16x32_bf16(a[kk], Brow[kk * 4 + quad], acc[c], 0, 0, 0);
        }
    }

    int rowbase = blockIdx.x * 64 + wave * 16 + quad * 4;
    #pragma unroll
    for (int c = 0; c < 8; ++c) {
        int ocol = c * 16 + mrow;
        float bv = bias[ocol];
        float scale = 0.f, shift = 0.f;
        if (DUAL) {
            scale = g[ocol] * rsqrtf(v[ocol] + 1e-3f);
            shift = be[ocol] - m[ocol] * scale;
        }
        #pragma unroll
        for (int r = 0; r < 4; ++r) {
            int orow = rowbase + r;
            float val = acc[c][r] + bv;
            if (RELU) val = fmaxf(val, 0.f);
            if (!DUAL) {
                out_bf[(size_t)orow * 128 + ocol] = f2bf(val);
            } else {
                float bnv = val * scale + shift;
                out_f32[(size_t)orow * 128 + ocol] = POOLBN ? bnv : val;
                out_bf[(size_t)orow * 128 + ocol] = f2bf(bnv);
            }
        }
    }
}

// ---------------- pooling ----------------
__global__ __launch_bounds__(128) void pool_kernel(const float* __restrict__ h,
                                                   const int* __restrict__ gidx,
                                                   float* __restrict__ pools, int col_off) {
    const int CHUNK = 64;
    int c = threadIdx.x;
    int i0 = blockIdx.x * CHUNK;
    float acc = 0.f;
    int cur_g = gidx[i0];
    for (int i = i0; i < i0 + CHUNK; ++i) {
        int gi = gidx[i];
        if (gi != cur_g) {
            atomicAdd(&pools[(size_t)cur_g * 640 + col_off + c], acc);
            acc = 0.f;
            cur_g = gi;
        }
        acc += h[(size_t)i * 128 + c];
    }
    atomicAdd(&pools[(size_t)cur_g * 640 + col_off + c], acc);
}

// ---------------- readout ----------------
__global__ __launch_bounds__(128) void readout1(const float* __restrict__ pools,
                                                const float* __restrict__ Wm1,
                                                const float* __restrict__ bm1,
                                                float* __restrict__ t2) {
    __shared__ float row[640];
    int gb = blockIdx.x;
    for (int k = threadIdx.x; k < 640; k += 128) row[k] = pools[(size_t)gb * 640 + k];
    __syncthreads();
    int j = threadIdx.x;
    float acc = bm1[j];
    for (int k = 0; k < 640; ++k) acc += row[k] * Wm1[(size_t)k * 128 + j];
    t2[(size_t)gb * 128 + j] = fmaxf(acc, 0.f);
}

__global__ __launch_bounds__(256) void readout2(const float* __restrict__ t2,
                                                const float* __restrict__ Wm2,
                                                const float* __restrict__ bm2,
                                                float* __restrict__ out) {
    int idx = blockIdx.x * 256 + threadIdx.x;
    if (idx < GG * 2) {
        int gb = idx >> 1, c = idx & 1;
        float acc = bm2[c];
        for (int k = 0; k < 128; ++k) acc += t2[(size_t)gb * 128 + k] * Wm2[k * 2 + c];
        out[idx] = acc;
    }
}

extern "C" void kernel_launch(void* const* d_in, const int* in_sizes, int n_in,
                              void* d_out, int out_size, void* d_ws, size_t ws_size,
                              hipStream_t stream) {
    const float* x  = (const float*)d_in[0];
    const float* ew = (const float*)d_in[1];
    const float *W1[5], *b1[5], *W2[5], *b2[5];
    for (int l = 0; l < 5; ++l) {
        W1[l] = (const float*)d_in[2 + 4 * l];
        b1[l] = (const float*)d_in[3 + 4 * l];
        W2[l] = (const float*)d_in[4 + 4 * l];
        b2[l] = (const float*)d_in[5 + 4 * l];
    }
    const float *bg[3], *bb[3], *bm[3], *bv[3];
    for (int j = 0; j < 3; ++j) {
        bg[j] = (const float*)d_in[22 + 4 * j];
        bb[j] = (const float*)d_in[23 + 4 * j];
        bm[j] = (const float*)d_in[24 + 4 * j];
        bv[j] = (const float*)d_in[25 + 4 * j];
    }
    const float* Wm1 = (const float*)d_in[34];
    const float* bm1 = (const float*)d_in[35];
    const float* Wm2 = (const float*)d_in[36];
    const float* bm2 = (const float*)d_in[37];
    const int* edge_index = (const int*)d_in[38];
    const int* src = edge_index;
    const int* dst = edge_index + EE;
    const int* gidx = (const int*)d_in[39];

    char* p = (char*)d_ws;
    auto alloc = [&](size_t bytes) -> void* {
        void* r = (void*)p;
        p += (bytes + 255) & ~(size_t)255;
        return r;
    };
    int2*  csr       = (int2*)alloc((size_t)EE * 8);
    int*   row_start = (int*)alloc((NN + 1) * 4);
    int*   cnt       = (int*)alloc(NN * 4);
    int*   cursor    = (int*)alloc(NN * 4);
    unsigned short* xb   = (unsigned short*)alloc((size_t)NN * 64 * 2);
    unsigned short* h2   = (unsigned short*)alloc((size_t)NN * 128 * 2);
    unsigned short* t    = (unsigned short*)alloc((size_t)NN * 128 * 2);
    unsigned short* h_bn = (unsigned short*)alloc((size_t)NN * 128 * 2);
    float* h_raw = (float*)alloc((size_t)NN * 128 * 4);
    float* pools = (float*)alloc((size_t)GG * 640 * 4);
    float* t2    = (float*)alloc((size_t)GG * 128 * 4);
    unsigned short* W1t[5], *W2t[5];
    for (int l = 0; l < 5; ++l) {
        W1t[l] = (unsigned short*)alloc((size_t)128 * 128 * 2);
        W2t[l] = (unsigned short*)alloc((size_t)128 * 128 * 2);
    }

    hipMemsetAsync(cnt, 0, NN * 4, stream);
    hipMemsetAsync(pools, 0, (size_t)GG * 640 * 4, stream);

    // convert weights (transposed to [n][k]) + x to bf16
    WJobs jobs;
    for (int l = 0; l < 5; ++l) {
        jobs.j[2 * l]     = WJob{W1[l], W1t[l], (l == 0) ? 64 : 128};
        jobs.j[2 * l + 1] = WJob{W2[l], W2t[l], 128};
    }
    convert_w<<<10, 256, 0, stream>>>(jobs);
    convert_x<<<(NN * 64) / 256, 256, 0, stream>>>(x, xb);

    count_kernel<<<EE / 256, 256, 0, stream>>>(src, cnt);
    scan_kernel<<<1, 1024, 0, stream>>>(cnt, row_start);
    hipMemcpyAsync(cursor, row_start, NN * 4, hipMemcpyDeviceToDevice, stream);
    fill_kernel<<<EE / 256, 256, 0, stream>>>(src, dst, ew, cursor, csr);

    // bn applied AFTER layer l: l=0->bn1, 1->bn1, 2->bn2, 3->bn3, 4->bn3
    const int bnsel[5] = {0, 0, 1, 2, 2};

    const unsigned short* h_in = xb;
    for (int l = 0; l < 5; ++l) {
        int s = bnsel[l];
        if (l == 0) {
            aggregate_bf<64><<<NN / 4, 256, 0, stream>>>(h_in, row_start, csr, h2);
            gemm_mfma<64, true, false, false><<<NN / 64, 256, 0, stream>>>(
                h2, W1t[0], b1[0], t, nullptr, nullptr, nullptr, nullptr, nullptr);
        } else {
            aggregate_bf<128><<<NN / 4, 256, 0, stream>>>(h_in, row_start, csr, h2);
            gemm_mfma<128, true, false, false><<<NN / 64, 256, 0, stream>>>(
                h2, W1t[l], b1[l], t, nullptr, nullptr, nullptr, nullptr, nullptr);
        }
        if (l < 4) {
            gemm_mfma<128, false, true, false><<<NN / 64, 256, 0, stream>>>(
                t, W2t[l], b2[l], h_bn, h_raw, bg[s], bb[s], bm[s], bv[s]);
        } else {
            gemm_mfma<128, false, true, true><<<NN / 64, 256, 0, stream>>>(
                t, W2t[l], b2[l], h_bn, h_raw, bg[s], bb[s], bm[s], bv[s]);
        }
        pool_kernel<<<NN / 64, 128, 0, stream>>>(h_raw, gidx, pools, l * 128);
        h_in = h_bn;
    }

    readout1<<<GG, 128, 0, stream>>>(pools, Wm1, bm1, t2);
    readout2<<<(GG * 2 + 255) / 256, 256, 0, stream>>>(t2, Wm2, bm2, (float*)d_out);
}